// Round 1
// baseline (196.133 us; speedup 1.0000x reference)
//
#include <hip/hip_runtime.h>
#include <cstdint>
#include <cstddef>

typedef __attribute__((ext_vector_type(8))) short bf16x8;
typedef __attribute__((ext_vector_type(4))) float f32x4;
typedef __attribute__((ext_vector_type(4))) unsigned int u32x4;
typedef __attribute__((ext_vector_type(2))) unsigned int u32x2;

__device__ __forceinline__ unsigned short f2bf(float f) {
    union { float f; unsigned int u; } c; c.f = f;
    unsigned int r = c.u + 0x7FFFu + ((c.u >> 16) & 1u);
    return (unsigned short)(r >> 16);
}
__device__ __forceinline__ unsigned int pack2bf(float a, float b) {
    return (unsigned int)f2bf(a) | ((unsigned int)f2bf(b) << 16);
}

// ---------------- convert x: fp32 -> bf16, straight ----------------
__global__ __launch_bounds__(256) void cvt_x_kernel(const float* __restrict__ src,
                                                    unsigned short* __restrict__ dst) {
    int e = (blockIdx.x * 256 + threadIdx.x) * 8;
    const float4* s4 = reinterpret_cast<const float4*>(src + e);
    float4 a = s4[0], b = s4[1];
    u32x4 o;
    o.x = pack2bf(a.x, a.y); o.y = pack2bf(a.z, a.w);
    o.z = pack2bf(b.x, b.y); o.w = pack2bf(b.z, b.w);
    *reinterpret_cast<u32x4*>(dst + e) = o;
}

// ---------------- convert W: fp32 [k][n] -> bf16 Wt [n][k] ----------------
__global__ __launch_bounds__(256) void cvt_w_kernel(const float* __restrict__ w0,
    const float* __restrict__ w1, const float* __restrict__ w2, const float* __restrict__ w3,
    unsigned short* __restrict__ dstbase) {
    __shared__ unsigned short sm[64][68];
    int z = blockIdx.y;
    const float* src = (z == 0) ? w0 : (z == 1) ? w1 : (z == 2) ? w2 : w3;
    unsigned short* dst = dstbase + (size_t)z * 1048576;
    int n0 = (blockIdx.x & 15) * 64;
    int k0 = (blockIdx.x >> 4) * 64;
    int tid = threadIdx.x;
    #pragma unroll
    for (int i = 0; i < 4; i++) {
        int e = i * 1024 + tid * 4;
        int r = e >> 6, c = e & 63;          // r = k row, c = n col
        float4 v = *reinterpret_cast<const float4*>(src + (size_t)(k0 + r) * 1024 + n0 + c);
        u32x2 p; p.x = pack2bf(v.x, v.y); p.y = pack2bf(v.z, v.w);
        *reinterpret_cast<u32x2*>(&sm[r][c]) = p;
    }
    __syncthreads();
    #pragma unroll
    for (int i = 0; i < 4; i++) {
        int e = i * 1024 + tid * 4;
        int n = e >> 6, kk = e & 63;
        u32x2 p;
        p.x = (unsigned)sm[kk][n]     | ((unsigned)sm[kk + 1][n] << 16);
        p.y = (unsigned)sm[kk + 2][n] | ((unsigned)sm[kk + 3][n] << 16);
        *reinterpret_cast<u32x2*>(dst + (size_t)(n0 + n) * 1024 + k0 + kk) = p;
    }
}

// ---------------- shared 128x128 GEMM mainloop (A[m][k], Wt[n][k], K=1024) -------------
__device__ __forceinline__ void gemm128_main(
    const unsigned short* __restrict__ A, const unsigned short* __restrict__ Wt,
    int m0, int n0, int tid,
    unsigned short (*Asm)[72], unsigned short (*Bsm)[72],
    f32x4 acc[4][4])
{
    const int lane = tid & 63;
    const int w = tid >> 6;
    const int wm = w >> 1, wn = w & 1;
    const int lr = lane & 15, lg = lane >> 4;
    for (int k0 = 0; k0 < 1024; k0 += 64) {
        __syncthreads();
        #pragma unroll
        for (int i = 0; i < 4; i++) {
            int e = i * 2048 + tid * 8;
            int r = e >> 6, c = e & 63;
            *reinterpret_cast<u32x4*>(&Asm[r][c]) =
                *reinterpret_cast<const u32x4*>(A + (size_t)(m0 + r) * 1024 + k0 + c);
            *reinterpret_cast<u32x4*>(&Bsm[r][c]) =
                *reinterpret_cast<const u32x4*>(Wt + (size_t)(n0 + r) * 1024 + k0 + c);
        }
        __syncthreads();
        #pragma unroll
        for (int ks = 0; ks < 2; ks++) {
            bf16x8 af[4], bf[4];
            #pragma unroll
            for (int t = 0; t < 4; t++) {
                af[t] = *reinterpret_cast<const bf16x8*>(&Asm[wm * 64 + t * 16 + lr][ks * 32 + lg * 8]);
                bf[t] = *reinterpret_cast<const bf16x8*>(&Bsm[wn * 64 + t * 16 + lr][ks * 32 + lg * 8]);
            }
            #pragma unroll
            for (int mt = 0; mt < 4; mt++) {
                #pragma unroll
                for (int nt = 0; nt < 4; nt++)
                    acc[mt][nt] = __builtin_amdgcn_mfma_f32_16x16x32_bf16(af[mt], bf[nt], acc[mt][nt], 0, 0, 0);
            }
        }
    }
}

// ---------------- QKV projection: z=0 Q (scaled), z=1 K, z=2 V^T ----------------
__global__ __launch_bounds__(256) void gemm_qkv_kernel(
    const unsigned short* __restrict__ A, const unsigned short* __restrict__ WtBase,
    const float* __restrict__ bq, const float* __restrict__ bk, const float* __restrict__ bv,
    unsigned short* __restrict__ Qo, unsigned short* __restrict__ Ko, unsigned short* __restrict__ Vto)
{
    __shared__ unsigned short Asm[128][72];
    __shared__ unsigned short Bsm[128][72];
    const int z = blockIdx.z;
    const unsigned short* Wt = WtBase + (size_t)z * 1048576;
    const float* bias = (z == 0) ? bq : (z == 1) ? bk : bv;
    const int m0 = blockIdx.y * 128, n0 = blockIdx.x * 128;
    const int tid = threadIdx.x, lane = tid & 63, w = tid >> 6;
    const int wm = w >> 1, wn = w & 1, lr = lane & 15, lg = lane >> 4;
    f32x4 acc[4][4];
    f32x4 zero4 = {0.f, 0.f, 0.f, 0.f};
    #pragma unroll
    for (int i = 0; i < 4; i++) {
        #pragma unroll
        for (int j = 0; j < 4; j++) acc[i][j] = zero4;
    }
    gemm128_main(A, Wt, m0, n0, tid, Asm, Bsm, acc);

    const float qs = 0.125f * 1.44269504088896341f;  // 1/sqrt(64) * log2(e)
    #pragma unroll
    for (int mt = 0; mt < 4; mt++) {
        #pragma unroll
        for (int nt = 0; nt < 4; nt++) {
            int gn = n0 + wn * 64 + nt * 16 + lr;
            int h = gn >> 6, d = gn & 63;
            int rb = m0 + wm * 64 + mt * 16 + lg * 4;
            int b_ = rb >> 11, s = rb & 2047;
            float bv_ = bias[gn];
            if (z == 2) {
                // V^T [B,H,D,S]: 4 consecutive s -> one 8B store
                u32x2 p;
                p.x = pack2bf(acc[mt][nt][0] + bv_, acc[mt][nt][1] + bv_);
                p.y = pack2bf(acc[mt][nt][2] + bv_, acc[mt][nt][3] + bv_);
                *reinterpret_cast<u32x2*>(Vto + ((size_t)(b_ * 16 + h) * 64 + d) * 2048 + s) = p;
            } else {
                unsigned short* dst = (z == 0) ? Qo : Ko;
                float sc_ = (z == 0) ? qs : 1.0f;
                #pragma unroll
                for (int r = 0; r < 4; r++)
                    dst[((size_t)(b_ * 16 + h) * 2048 + (s + r)) * 64 + d] = f2bf((acc[mt][nt][r] + bv_) * sc_);
            }
        }
    }
}

// ---------------- flash attention: Q[B,H,S,D] (pre-scaled), K[B,H,S,D], Vt[B,H,D,S] ----
__global__ __launch_bounds__(256) void attn_kernel(
    const unsigned short* __restrict__ Qg,
    const unsigned short* __restrict__ Kg,
    const unsigned short* __restrict__ Vtg,
    unsigned short* __restrict__ Og)
{
    __shared__ unsigned short Ksm[128][72];
    __shared__ unsigned short Vsm[64][136];
    __shared__ unsigned short Psm[4][32][136];

    const int tid = threadIdx.x;
    const int lane = tid & 63;
    const int w = tid >> 6;
    const int lr = lane & 15, lg = lane >> 4;
    const int bh = blockIdx.y;
    const int q0 = blockIdx.x * 128;
    const size_t kvbase = (size_t)bh * 2048 * 64;
    const size_t vtbase = (size_t)bh * 64 * 2048;

    // stage Q through Ksm once
    #pragma unroll
    for (int i = 0; i < 4; i++) {
        int e = i * 2048 + tid * 8;
        int r = e >> 6, c = e & 63;
        *reinterpret_cast<u32x4*>(&Ksm[r][c]) =
            *reinterpret_cast<const u32x4*>(Qg + kvbase + (size_t)(q0 + r) * 64 + c);
    }
    __syncthreads();
    bf16x8 qf[2][2];
    #pragma unroll
    for (int mt = 0; mt < 2; mt++) {
        #pragma unroll
        for (int ks = 0; ks < 2; ks++)
            qf[mt][ks] = *reinterpret_cast<const bf16x8*>(&Ksm[w * 32 + mt * 16 + lr][ks * 32 + lg * 8]);
    }
    __syncthreads();

    f32x4 oacc[2][4];
    float mrun[2][4], lrun[2][4];
    f32x4 zero4 = {0.f, 0.f, 0.f, 0.f};
    #pragma unroll
    for (int mt = 0; mt < 2; mt++) {
        #pragma unroll
        for (int nd = 0; nd < 4; nd++) oacc[mt][nd] = zero4;
        #pragma unroll
        for (int r = 0; r < 4; r++) { mrun[mt][r] = -3.0e38f; lrun[mt][r] = 0.f; }
    }

    for (int kt = 0; kt < 16; kt++) {
        int kv0 = kt * 128;
        #pragma unroll
        for (int i = 0; i < 4; i++) {
            int e = i * 2048 + tid * 8;
            {
                int r = e >> 6, c = e & 63;
                *reinterpret_cast<u32x4*>(&Ksm[r][c]) =
                    *reinterpret_cast<const u32x4*>(Kg + kvbase + (size_t)(kv0 + r) * 64 + c);
            }
            {
                int d = e >> 7, c = e & 127;
                *reinterpret_cast<u32x4*>(&Vsm[d][c]) =
                    *reinterpret_cast<const u32x4*>(Vtg + vtbase + (size_t)d * 2048 + kv0 + c);
            }
        }
        __syncthreads();

        // QK^T: scores[2 mt][8 nt]
        f32x4 sc[2][8];
        #pragma unroll
        for (int mt = 0; mt < 2; mt++) {
            #pragma unroll
            for (int nt = 0; nt < 8; nt++) sc[mt][nt] = zero4;
        }
        #pragma unroll
        for (int ks = 0; ks < 2; ks++) {
            bf16x8 kf[8];
            #pragma unroll
            for (int nt = 0; nt < 8; nt++)
                kf[nt] = *reinterpret_cast<const bf16x8*>(&Ksm[nt * 16 + lr][ks * 32 + lg * 8]);
            #pragma unroll
            for (int mt = 0; mt < 2; mt++) {
                #pragma unroll
                for (int nt = 0; nt < 8; nt++)
                    sc[mt][nt] = __builtin_amdgcn_mfma_f32_16x16x32_bf16(qf[mt][ks], kf[nt], sc[mt][nt], 0, 0, 0);
            }
        }

        // online softmax (log2 domain; Q pre-scaled by 0.125*log2e)
        #pragma unroll
        for (int mt = 0; mt < 2; mt++) {
            #pragma unroll
            for (int r = 0; r < 4; r++) {
                float mx = sc[mt][0][r];
                #pragma unroll
                for (int nt = 1; nt < 8; nt++) mx = fmaxf(mx, sc[mt][nt][r]);
                #pragma unroll
                for (int s_ = 1; s_ < 16; s_ <<= 1) mx = fmaxf(mx, __shfl_xor(mx, s_));
                float mnew = fmaxf(mrun[mt][r], mx);
                float f = __builtin_amdgcn_exp2f(mrun[mt][r] - mnew);
                float psum = 0.f;
                #pragma unroll
                for (int nt = 0; nt < 8; nt++) {
                    float p = __builtin_amdgcn_exp2f(sc[mt][nt][r] - mnew);
                    psum += p;
                    Psm[w][mt * 16 + lg * 4 + r][nt * 16 + lr] = f2bf(p);
                }
                #pragma unroll
                for (int s_ = 1; s_ < 16; s_ <<= 1) psum += __shfl_xor(psum, s_);
                lrun[mt][r] = lrun[mt][r] * f + psum;
                mrun[mt][r] = mnew;
                #pragma unroll
                for (int nd = 0; nd < 4; nd++) oacc[mt][nd][r] *= f;
            }
        }

        // PV: oacc += P @ V
        #pragma unroll
        for (int ks = 0; ks < 4; ks++) {
            bf16x8 vf[4];
            #pragma unroll
            for (int nd = 0; nd < 4; nd++)
                vf[nd] = *reinterpret_cast<const bf16x8*>(&Vsm[nd * 16 + lr][ks * 32 + lg * 8]);
            #pragma unroll
            for (int mt = 0; mt < 2; mt++) {
                bf16x8 pf = *reinterpret_cast<const bf16x8*>(&Psm[w][mt * 16 + lr][ks * 32 + lg * 8]);
                #pragma unroll
                for (int nd = 0; nd < 4; nd++)
                    oacc[mt][nd] = __builtin_amdgcn_mfma_f32_16x16x32_bf16(pf, vf[nd], oacc[mt][nd], 0, 0, 0);
            }
        }
        __syncthreads();
    }

    // normalize + write Obuf [B,S,H*D] bf16
    const int b_ = bh >> 4, h = bh & 15;
    #pragma unroll
    for (int mt = 0; mt < 2; mt++) {
        #pragma unroll
        for (int r = 0; r < 4; r++) {
            float inv = 1.0f / lrun[mt][r];
            int s = q0 + w * 32 + mt * 16 + lg * 4 + r;
            #pragma unroll
            for (int nd = 0; nd < 4; nd++) {
                int d = nd * 16 + lr;
                Og[((size_t)b_ * 2048 + s) * 1024 + h * 64 + d] = f2bf(oacc[mt][nd][r] * inv);
            }
        }
    }
}

// ---------------- output projection: Obuf @ Wo^T + bo -> fp32 out ----------------
__global__ __launch_bounds__(256) void gemm_out_kernel(
    const unsigned short* __restrict__ A, const unsigned short* __restrict__ Wt,
    const float* __restrict__ bias, float* __restrict__ out)
{
    __shared__ unsigned short Asm[128][72];
    __shared__ unsigned short Bsm[128][72];
    const int m0 = blockIdx.y * 128, n0 = blockIdx.x * 128;
    const int tid = threadIdx.x, lane = tid & 63, w = tid >> 6;
    const int wm = w >> 1, wn = w & 1, lr = lane & 15, lg = lane >> 4;
    f32x4 acc[4][4];
    f32x4 zero4 = {0.f, 0.f, 0.f, 0.f};
    #pragma unroll
    for (int i = 0; i < 4; i++) {
        #pragma unroll
        for (int j = 0; j < 4; j++) acc[i][j] = zero4;
    }
    gemm128_main(A, Wt, m0, n0, tid, Asm, Bsm, acc);
    #pragma unroll
    for (int mt = 0; mt < 4; mt++) {
        #pragma unroll
        for (int nt = 0; nt < 4; nt++) {
            int gn = n0 + wn * 64 + nt * 16 + lr;
            float bv_ = bias[gn];
            int rb = m0 + wm * 64 + mt * 16 + lg * 4;
            #pragma unroll
            for (int r = 0; r < 4; r++)
                out[(size_t)(rb + r) * 1024 + gn] = acc[mt][nt][r] + bv_;
        }
    }
}

extern "C" void kernel_launch(void* const* d_in, const int* in_sizes, int n_in,
                              void* d_out, int out_size, void* d_ws, size_t ws_size,
                              hipStream_t stream) {
    const float* x  = (const float*)d_in[0];
    const float* Wq = (const float*)d_in[1];
    const float* bq = (const float*)d_in[2];
    const float* Wk = (const float*)d_in[3];
    const float* bk = (const float*)d_in[4];
    const float* Wv = (const float*)d_in[5];
    const float* bv = (const float*)d_in[6];
    const float* Wo = (const float*)d_in[7];
    const float* bo = (const float*)d_in[8];
    float* out = (float*)d_out;

    if (ws_size < (size_t)25165824 * 2) return;  // need 48 MB
    unsigned short* ws  = (unsigned short*)d_ws;
    unsigned short* xbf = ws;                    // [4096][1024]
    unsigned short* wt  = ws + 4194304;          // 4x [1024][1024] transposed
    unsigned short* Qb  = ws + 8388608;          // [B,H,S,D]
    unsigned short* Kb  = ws + 12582912;         // [B,H,S,D]
    unsigned short* Vtb = ws + 16777216;         // [B,H,D,S]
    unsigned short* Ob  = ws + 20971520;         // [B,S,E]

    cvt_x_kernel<<<2048, 256, 0, stream>>>(x, xbf);
    cvt_w_kernel<<<dim3(256, 4), 256, 0, stream>>>(Wq, Wk, Wv, Wo, wt);
    gemm_qkv_kernel<<<dim3(8, 32, 3), 256, 0, stream>>>(xbf, wt, bq, bk, bv, Qb, Kb, Vtb);
    attn_kernel<<<dim3(16, 32), 256, 0, stream>>>(Qb, Kb, Vtb, Ob);
    gemm_out_kernel<<<dim3(8, 32), 256, 0, stream>>>(Ob, wt + 3 * 1048576, bo, out);
}

// Round 3
// 136.657 us; speedup vs baseline: 1.4352x; 1.4352x over previous
//
#include <hip/hip_runtime.h>
#include <cstdint>
#include <cstddef>

typedef __attribute__((ext_vector_type(8))) short bf16x8;
typedef __attribute__((ext_vector_type(4))) float f32x4;
typedef __attribute__((ext_vector_type(16))) float f32x16;
typedef __attribute__((ext_vector_type(4))) unsigned int u32x4;
typedef __attribute__((ext_vector_type(2))) unsigned int u32x2;

__device__ __forceinline__ unsigned short f2bf(float f) {
    union { float f; unsigned int u; } c; c.f = f;
    unsigned int r = c.u + 0x7FFFu + ((c.u >> 16) & 1u);
    return (unsigned short)(r >> 16);
}
__device__ __forceinline__ unsigned int pack2bf(float a, float b) {
    return (unsigned int)f2bf(a) | ((unsigned int)f2bf(b) << 16);
}
__device__ __forceinline__ unsigned int cvtpk(float lo, float hi) {
    unsigned int r;
    asm("v_cvt_pk_bf16_f32 %0, %1, %2" : "=v"(r) : "v"(lo), "v"(hi));
    return r;
}

// ---------------- convert x: fp32 -> bf16 ----------------
__global__ __launch_bounds__(256) void cvt_x_kernel(const float* __restrict__ src,
                                                    unsigned short* __restrict__ dst) {
    int e = (blockIdx.x * 256 + threadIdx.x) * 8;
    const float4* s4 = reinterpret_cast<const float4*>(src + e);
    float4 a = s4[0], b = s4[1];
    u32x4 o;
    o.x = pack2bf(a.x, a.y); o.y = pack2bf(a.z, a.w);
    o.z = pack2bf(b.x, b.y); o.w = pack2bf(b.z, b.w);
    *reinterpret_cast<u32x4*>(dst + e) = o;
}

// ---------------- convert W: fp32 [k][n] -> bf16 Wt [n][k] ----------------
__global__ __launch_bounds__(256) void cvt_w_kernel(const float* __restrict__ w0,
    const float* __restrict__ w1, const float* __restrict__ w2, const float* __restrict__ w3,
    unsigned short* __restrict__ dstbase) {
    __shared__ unsigned short sm[64][68];
    int z = blockIdx.y;
    const float* src = (z == 0) ? w0 : (z == 1) ? w1 : (z == 2) ? w2 : w3;
    unsigned short* dst = dstbase + (size_t)z * 1048576;
    int n0 = (blockIdx.x & 15) * 64;
    int k0 = (blockIdx.x >> 4) * 64;
    int tid = threadIdx.x;
    #pragma unroll
    for (int i = 0; i < 4; i++) {
        int e = i * 1024 + tid * 4;
        int r = e >> 6, c = e & 63;
        float4 v = *reinterpret_cast<const float4*>(src + (size_t)(k0 + r) * 1024 + n0 + c);
        u32x2 p; p.x = pack2bf(v.x, v.y); p.y = pack2bf(v.z, v.w);
        *reinterpret_cast<u32x2*>(&sm[r][c]) = p;
    }
    __syncthreads();
    #pragma unroll
    for (int i = 0; i < 4; i++) {
        int e = i * 1024 + tid * 4;
        int n = e >> 6, kk = e & 63;
        u32x2 p;
        p.x = (unsigned)sm[kk][n]     | ((unsigned)sm[kk + 1][n] << 16);
        p.y = (unsigned)sm[kk + 2][n] | ((unsigned)sm[kk + 3][n] << 16);
        *reinterpret_cast<u32x2*>(dst + (size_t)(n0 + n) * 1024 + k0 + kk) = p;
    }
}

// ------- 128x128 GEMM mainloop (round-1 proven reg-staged version) -------
__device__ __forceinline__ void gemm128_main(
    const unsigned short* __restrict__ A, const unsigned short* __restrict__ Wt,
    int m0, int n0, int tid,
    unsigned short (*Asm)[72], unsigned short (*Bsm)[72],
    f32x4 acc[4][4])
{
    const int lane = tid & 63;
    const int w = tid >> 6;
    const int wm = w >> 1, wn = w & 1;
    const int lr = lane & 15, lg = lane >> 4;
    for (int k0 = 0; k0 < 1024; k0 += 64) {
        __syncthreads();
        #pragma unroll
        for (int i = 0; i < 4; i++) {
            int e = i * 2048 + tid * 8;
            int r = e >> 6, c = e & 63;
            *reinterpret_cast<u32x4*>(&Asm[r][c]) =
                *reinterpret_cast<const u32x4*>(A + (size_t)(m0 + r) * 1024 + k0 + c);
            *reinterpret_cast<u32x4*>(&Bsm[r][c]) =
                *reinterpret_cast<const u32x4*>(Wt + (size_t)(n0 + r) * 1024 + k0 + c);
        }
        __syncthreads();
        #pragma unroll
        for (int ks = 0; ks < 2; ks++) {
            bf16x8 af[4], bfr[4];
            #pragma unroll
            for (int t = 0; t < 4; t++) {
                af[t]  = *reinterpret_cast<const bf16x8*>(&Asm[wm * 64 + t * 16 + lr][ks * 32 + lg * 8]);
                bfr[t] = *reinterpret_cast<const bf16x8*>(&Bsm[wn * 64 + t * 16 + lr][ks * 32 + lg * 8]);
            }
            #pragma unroll
            for (int mt = 0; mt < 4; mt++) {
                #pragma unroll
                for (int nt = 0; nt < 4; nt++)
                    acc[mt][nt] = __builtin_amdgcn_mfma_f32_16x16x32_bf16(af[mt], bfr[nt], acc[mt][nt], 0, 0, 0);
            }
        }
    }
}

// ---------------- QKV projection: z=0 Q (scaled), z=1 K, z=2 V^T ----------------
__global__ __launch_bounds__(256) void gemm_qkv_kernel(
    const unsigned short* __restrict__ A, const unsigned short* __restrict__ WtBase,
    const float* __restrict__ bq, const float* __restrict__ bk, const float* __restrict__ bv,
    unsigned short* __restrict__ Qo, unsigned short* __restrict__ Ko, unsigned short* __restrict__ Vto)
{
    __shared__ unsigned short Asm[128][72];
    __shared__ unsigned short Bsm[128][72];
    const int z = blockIdx.z;
    const unsigned short* Wt = WtBase + (size_t)z * 1048576;
    const float* bias = (z == 0) ? bq : (z == 1) ? bk : bv;
    const int m0 = blockIdx.y * 128, n0 = blockIdx.x * 128;
    const int tid = threadIdx.x, lane = tid & 63, w = tid >> 6;
    const int wm = w >> 1, wn = w & 1, lr = lane & 15, lg = lane >> 4;
    f32x4 acc[4][4];
    f32x4 zero4 = {0.f, 0.f, 0.f, 0.f};
    #pragma unroll
    for (int i = 0; i < 4; i++)
        #pragma unroll
        for (int j = 0; j < 4; j++) acc[i][j] = zero4;
    gemm128_main(A, Wt, m0, n0, tid, Asm, Bsm, acc);

    const float qs = 0.125f * 1.44269504088896341f;  // 1/sqrt(64) * log2(e)
    #pragma unroll
    for (int mt = 0; mt < 4; mt++) {
        #pragma unroll
        for (int nt = 0; nt < 4; nt++) {
            int gn = n0 + wn * 64 + nt * 16 + lr;
            int h = gn >> 6, d = gn & 63;
            int rb = m0 + wm * 64 + mt * 16 + lg * 4;
            int b_ = rb >> 11, s = rb & 2047;
            float bv_ = bias[gn];
            if (z == 2) {
                u32x2 p;
                p.x = pack2bf(acc[mt][nt][0] + bv_, acc[mt][nt][1] + bv_);
                p.y = pack2bf(acc[mt][nt][2] + bv_, acc[mt][nt][3] + bv_);
                *reinterpret_cast<u32x2*>(Vto + ((size_t)(b_ * 16 + h) * 64 + d) * 2048 + s) = p;
            } else {
                unsigned short* dst = (z == 0) ? Qo : Ko;
                float sc_ = (z == 0) ? qs : 1.0f;
                #pragma unroll
                for (int r = 0; r < 4; r++)
                    dst[((size_t)(b_ * 16 + h) * 2048 + (s + r)) * 64 + d] = f2bf((acc[mt][nt][r] + bv_) * sc_);
            }
        }
    }
}

// ------- flash attention: swapped QK^T (32x32x16), in-register softmax -------
// Exchange across lane^32 via __shfl_xor (unambiguous), selects are compile-time-indexed.
__global__ __launch_bounds__(256, 2) void attn_kernel(
    const unsigned short* __restrict__ Qg,
    const unsigned short* __restrict__ Kg,
    const unsigned short* __restrict__ Vtg,
    unsigned short* __restrict__ Og)
{
    __shared__ unsigned short Ksm[128][72];
    __shared__ unsigned short Vsm[64][136];

    const int tid = threadIdx.x, lane = tid & 63, w = tid >> 6;
    const int l31 = lane & 31, L = lane >> 5;
    const int bh = blockIdx.y, q0 = blockIdx.x * 128;
    const size_t kvbase = (size_t)bh * (2048 * 64);
    const size_t vtbase = (size_t)bh * (64 * 2048);

    // ---- stage Q through Ksm, read q fragments (B-operand layout) ----
    {
        u32x4 qr[4];
        #pragma unroll
        for (int i = 0; i < 4; i++) {
            int ck = i * 256 + tid; int r = ck >> 3, c = (ck & 7) * 8;
            qr[i] = *reinterpret_cast<const u32x4*>(Qg + kvbase + (size_t)(q0 + r) * 64 + c);
        }
        #pragma unroll
        for (int i = 0; i < 4; i++) {
            int ck = i * 256 + tid; int r = ck >> 3, c = (ck & 7) * 8;
            *reinterpret_cast<u32x4*>(&Ksm[r][c]) = qr[i];
        }
    }
    __syncthreads();
    bf16x8 qf[4];
    #pragma unroll
    for (int ds = 0; ds < 4; ds++)
        qf[ds] = *reinterpret_cast<const bf16x8*>(&Ksm[w * 32 + l31][ds * 16 + L * 8]);
    __syncthreads();

    f32x16 oacc[2];
    #pragma unroll
    for (int dt = 0; dt < 2; dt++)
        #pragma unroll
        for (int j = 0; j < 16; j++) oacc[dt][j] = 0.f;
    float m_run = -3.0e38f, l_run = 0.f;

    u32x4 kreg[4], vreg[4];
#define LOAD_TILE(KV0)                                                                      \
    _Pragma("unroll")                                                                       \
    for (int i = 0; i < 4; i++) {                                                           \
        int ck = i * 256 + tid; int r = ck >> 3, c = (ck & 7) * 8;                          \
        kreg[i] = *reinterpret_cast<const u32x4*>(Kg + kvbase + (size_t)((KV0) + r) * 64 + c); \
        int dv = ck >> 4, cv = (ck & 15) * 8;                                               \
        vreg[i] = *reinterpret_cast<const u32x4*>(Vtg + vtbase + (size_t)dv * 2048 + (KV0) + cv); \
    }

    LOAD_TILE(0)
    for (int kt = 0; kt < 16; kt++) {
        #pragma unroll
        for (int i = 0; i < 4; i++) {
            int ck = i * 256 + tid; int r = ck >> 3, c = (ck & 7) * 8;
            *reinterpret_cast<u32x4*>(&Ksm[r][c]) = kreg[i];
            int dv = ck >> 4, cv = (ck & 15) * 8;
            *reinterpret_cast<u32x4*>(&Vsm[dv][cv]) = vreg[i];
        }
        __syncthreads();
        int kvn = (kt < 15) ? (kt + 1) * 128 : 0;
        LOAD_TILE(kvn)   // prefetch next tile into regs, consumed next iteration

        // ---- QK^T swapped: sc[nt] = K_tile(A) x Q(B); lane owns q = w*32+l31 ----
        f32x16 sc[4];
        #pragma unroll
        for (int nt = 0; nt < 4; nt++) {
            #pragma unroll
            for (int j = 0; j < 16; j++) sc[nt][j] = 0.f;
            #pragma unroll
            for (int ds = 0; ds < 4; ds++) {
                bf16x8 kf = *reinterpret_cast<const bf16x8*>(&Ksm[nt * 32 + l31][ds * 16 + L * 8]);
                sc[nt] = __builtin_amdgcn_mfma_f32_32x32x16_bf16(kf, qf[ds], sc[nt], 0, 0, 0);
            }
        }

        // ---- softmax: lane pair (l, l^32) shares q-row w*32+l31 ----
        float pmax = sc[0][0];
        #pragma unroll
        for (int nt = 0; nt < 4; nt++)
            #pragma unroll
            for (int j = 0; j < 16; j++) pmax = fmaxf(pmax, sc[nt][j]);
        pmax = fmaxf(pmax, __shfl_xor(pmax, 32));

        if (__any(pmax - m_run > 8.0f)) {   // defer-max (T13)
            float mnew = fmaxf(m_run, pmax);
            float f = __builtin_amdgcn_exp2f(m_run - mnew);
            l_run *= f;
            #pragma unroll
            for (int dt = 0; dt < 2; dt++)
                #pragma unroll
                for (int j = 0; j < 16; j++) oacc[dt][j] *= f;
            m_run = mnew;
        }

        float psum = 0.f;
        unsigned pdw[4][4][2];
        #pragma unroll
        for (int nt = 0; nt < 4; nt++) {
            float p[16];
            #pragma unroll
            for (int j = 0; j < 16; j++) {
                p[j] = __builtin_amdgcn_exp2f(sc[nt][j] - m_run);
                psum += p[j];
            }
            #pragma unroll
            for (int a = 0; a < 4; a++) {
                pdw[nt][a][0] = cvtpk(p[4 * a + 0], p[4 * a + 1]);
                pdw[nt][a][1] = cvtpk(p[4 * a + 2], p[4 * a + 3]);
            }
        }
        psum += __shfl_xor(psum, 32);
        l_run += psum;

        // ---- PV: oacc[dt] += V^T(A) x P^T(B); exchange via shfl_xor(.,32) ----
        // Lane L needs fragment k=8L+j: j0..3 from pair's L=0 lane quad (b2+L),
        // j4..7 from pair's L=1 lane quad (b2+L).
        #pragma unroll
        for (int kt2 = 0; kt2 < 8; kt2++) {
            const int nt = kt2 >> 1, b2 = (kt2 & 1) * 2;
            unsigned own0  = L ? pdw[nt][b2 + 1][0] : pdw[nt][b2][0];
            unsigned own1  = L ? pdw[nt][b2 + 1][1] : pdw[nt][b2][1];
            unsigned send0 = L ? pdw[nt][b2][0]     : pdw[nt][b2 + 1][0];
            unsigned send1 = L ? pdw[nt][b2][1]     : pdw[nt][b2 + 1][1];
            unsigned recv0 = (unsigned)__shfl_xor((int)send0, 32);
            unsigned recv1 = (unsigned)__shfl_xor((int)send1, 32);
            u32x4 pf4;
            pf4.x = L ? recv0 : own0;
            pf4.y = L ? recv1 : own1;
            pf4.z = L ? own0  : recv0;
            pf4.w = L ? own1  : recv1;
            bf16x8 pfr = *reinterpret_cast<bf16x8*>(&pf4);
            #pragma unroll
            for (int dt = 0; dt < 2; dt++) {
                bf16x8 vf = *reinterpret_cast<const bf16x8*>(&Vsm[dt * 32 + l31][kt2 * 16 + L * 8]);
                oacc[dt] = __builtin_amdgcn_mfma_f32_32x32x16_bf16(vf, pfr, oacc[dt], 0, 0, 0);
            }
        }
        __syncthreads();
    }
#undef LOAD_TILE

    // ---- epilogue: O^T in regs -> [B,S,E] bf16 stores ----
    float inv = 1.0f / l_run;
    const int b_ = bh >> 4, h = bh & 15;
    const int s = q0 + w * 32 + l31;
    unsigned short* orow = Og + ((size_t)b_ * 2048 + s) * 1024 + h * 64;
    #pragma unroll
    for (int dt = 0; dt < 2; dt++) {
        #pragma unroll
        for (int g = 0; g < 4; g++) {
            u32x2 pp;
            pp.x = cvtpk(oacc[dt][4 * g + 0] * inv, oacc[dt][4 * g + 1] * inv);
            pp.y = cvtpk(oacc[dt][4 * g + 2] * inv, oacc[dt][4 * g + 3] * inv);
            *reinterpret_cast<u32x2*>(orow + dt * 32 + g * 8 + 4 * L) = pp;
        }
    }
}

// ---------------- output projection: Obuf @ Wo^T + bo -> fp32 out ----------------
__global__ __launch_bounds__(256) void gemm_out_kernel(
    const unsigned short* __restrict__ A, const unsigned short* __restrict__ Wt,
    const float* __restrict__ bias, float* __restrict__ out)
{
    __shared__ unsigned short Asm[128][72];
    __shared__ unsigned short Bsm[128][72];
    const int m0 = blockIdx.y * 128, n0 = blockIdx.x * 128;
    const int tid = threadIdx.x, lane = tid & 63, w = tid >> 6;
    const int wm = w >> 1, wn = w & 1, lr = lane & 15, lg = lane >> 4;
    f32x4 acc[4][4];
    f32x4 zero4 = {0.f, 0.f, 0.f, 0.f};
    #pragma unroll
    for (int i = 0; i < 4; i++)
        #pragma unroll
        for (int j = 0; j < 4; j++) acc[i][j] = zero4;
    gemm128_main(A, Wt, m0, n0, tid, Asm, Bsm, acc);
    #pragma unroll
    for (int mt = 0; mt < 4; mt++) {
        #pragma unroll
        for (int nt = 0; nt < 4; nt++) {
            int gn = n0 + wn * 64 + nt * 16 + lr;
            float bv_ = bias[gn];
            int rb = m0 + wm * 64 + mt * 16 + lg * 4;
            #pragma unroll
            for (int r = 0; r < 4; r++)
                out[(size_t)(rb + r) * 1024 + gn] = acc[mt][nt][r] + bv_;
        }
    }
}

extern "C" void kernel_launch(void* const* d_in, const int* in_sizes, int n_in,
                              void* d_out, int out_size, void* d_ws, size_t ws_size,
                              hipStream_t stream) {
    const float* x  = (const float*)d_in[0];
    const float* Wq = (const float*)d_in[1];
    const float* bq = (const float*)d_in[2];
    const float* Wk = (const float*)d_in[3];
    const float* bk = (const float*)d_in[4];
    const float* Wv = (const float*)d_in[5];
    const float* bv = (const float*)d_in[6];
    const float* Wo = (const float*)d_in[7];
    const float* bo = (const float*)d_in[8];
    float* out = (float*)d_out;

    if (ws_size < (size_t)25165824 * 2) return;  // need 48 MB
    unsigned short* ws  = (unsigned short*)d_ws;
    unsigned short* xbf = ws;                    // [4096][1024]
    unsigned short* wt  = ws + 4194304;          // 4x [1024][1024] transposed
    unsigned short* Qb  = ws + 8388608;          // [B,H,S,D] (pre-scaled)
    unsigned short* Kb  = ws + 12582912;         // [B,H,S,D]
    unsigned short* Vtb = ws + 16777216;         // [B,H,D,S]
    unsigned short* Ob  = ws + 20971520;         // [B,S,E]

    cvt_x_kernel<<<2048, 256, 0, stream>>>(x, xbf);
    cvt_w_kernel<<<dim3(256, 4), 256, 0, stream>>>(Wq, Wk, Wv, Wo, wt);
    gemm_qkv_kernel<<<dim3(8, 32, 3), 256, 0, stream>>>(xbf, wt, bq, bk, bv, Qb, Kb, Vtb);
    attn_kernel<<<dim3(16, 32), 256, 0, stream>>>(Qb, Kb, Vtb, Ob);
    gemm_out_kernel<<<dim3(8, 32), 256, 0, stream>>>(Ob, wt + 3 * 1048576, bo, out);
}

// Round 4
// 136.355 us; speedup vs baseline: 1.4384x; 1.0022x over previous
//
#include <hip/hip_runtime.h>
#include <cstdint>
#include <cstddef>

typedef __attribute__((ext_vector_type(8))) short bf16x8;
typedef __attribute__((ext_vector_type(4))) float f32x4;
typedef __attribute__((ext_vector_type(16))) float f32x16;
typedef __attribute__((ext_vector_type(4))) unsigned int u32x4;
typedef __attribute__((ext_vector_type(2))) unsigned int u32x2;

__device__ __forceinline__ unsigned short f2bf(float f) {
    union { float f; unsigned int u; } c; c.f = f;
    unsigned int r = c.u + 0x7FFFu + ((c.u >> 16) & 1u);
    return (unsigned short)(r >> 16);
}
__device__ __forceinline__ unsigned int pack2bf(float a, float b) {
    return (unsigned int)f2bf(a) | ((unsigned int)f2bf(b) << 16);
}
__device__ __forceinline__ unsigned int cvtpk(float lo, float hi) {
    unsigned int r;
    asm("v_cvt_pk_bf16_f32 %0, %1, %2" : "=v"(r) : "v"(lo), "v"(hi));
    return r;
}
__device__ __forceinline__ void gload16(const void* g, void* l) {
    __builtin_amdgcn_global_load_lds((const __attribute__((address_space(1))) void*)g,
                                     (__attribute__((address_space(3))) void*)l, 16, 0, 0);
}

// ---------------- convert x: fp32 -> bf16 ----------------
__global__ __launch_bounds__(256) void cvt_x_kernel(const float* __restrict__ src,
                                                    unsigned short* __restrict__ dst) {
    int e = (blockIdx.x * 256 + threadIdx.x) * 8;
    const float4* s4 = reinterpret_cast<const float4*>(src + e);
    float4 a = s4[0], b = s4[1];
    u32x4 o;
    o.x = pack2bf(a.x, a.y); o.y = pack2bf(a.z, a.w);
    o.z = pack2bf(b.x, b.y); o.w = pack2bf(b.z, b.w);
    *reinterpret_cast<u32x4*>(dst + e) = o;
}

// ---------------- convert W: fp32 [k][n] -> bf16 Wt [n][k] ----------------
__global__ __launch_bounds__(256) void cvt_w_kernel(const float* __restrict__ w0,
    const float* __restrict__ w1, const float* __restrict__ w2, const float* __restrict__ w3,
    unsigned short* __restrict__ dstbase) {
    __shared__ unsigned short sm[64][68];
    int z = blockIdx.y;
    const float* src = (z == 0) ? w0 : (z == 1) ? w1 : (z == 2) ? w2 : w3;
    unsigned short* dst = dstbase + (size_t)z * 1048576;
    int n0 = (blockIdx.x & 15) * 64;
    int k0 = (blockIdx.x >> 4) * 64;
    int tid = threadIdx.x;
    #pragma unroll
    for (int i = 0; i < 4; i++) {
        int e = i * 1024 + tid * 4;
        int r = e >> 6, c = e & 63;
        float4 v = *reinterpret_cast<const float4*>(src + (size_t)(k0 + r) * 1024 + n0 + c);
        u32x2 p; p.x = pack2bf(v.x, v.y); p.y = pack2bf(v.z, v.w);
        *reinterpret_cast<u32x2*>(&sm[r][c]) = p;
    }
    __syncthreads();
    #pragma unroll
    for (int i = 0; i < 4; i++) {
        int e = i * 1024 + tid * 4;
        int n = e >> 6, kk = e & 63;
        u32x2 p;
        p.x = (unsigned)sm[kk][n]     | ((unsigned)sm[kk + 1][n] << 16);
        p.y = (unsigned)sm[kk + 2][n] | ((unsigned)sm[kk + 3][n] << 16);
        *reinterpret_cast<u32x2*>(dst + (size_t)(n0 + n) * 1024 + k0 + kk) = p;
    }
}

// ------- 128x128 GEMM mainloop, m97 structure: global_load_lds + XOR swizzle -------
// LDS linear: chunk L (16B) at row r=L>>3, slot cs=L&7 holds global column chunk cs^(r&7).
__device__ __forceinline__ void gemm128_main(
    const unsigned short* __restrict__ A, const unsigned short* __restrict__ Wt,
    int m0, int n0, int tid,
    unsigned short* Asm, unsigned short* Bsm,
    f32x4 acc[4][4])
{
    const int lane = tid & 63;
    const int w = tid >> 6;
    const int wm = w >> 1, wn = w & 1;
    const int lr = lane & 15, lg = lane >> 4;
    for (int k0 = 0; k0 < 1024; k0 += 64) {
        __syncthreads();
        #pragma unroll
        for (int i = 0; i < 4; i++) {
            int L = (i * 4 + w) * 64 + lane;
            int r = L >> 3, cs = L & 7;
            int c = cs ^ (r & 7);
            gload16(A  + (size_t)(m0 + r) * 1024 + k0 + c * 8, Asm + (i * 4 + w) * 512);
            gload16(Wt + (size_t)(n0 + r) * 1024 + k0 + c * 8, Bsm + (i * 4 + w) * 512);
        }
        __syncthreads();
        #pragma unroll
        for (int ks = 0; ks < 2; ks++) {
            bf16x8 af[4], bfr[4];
            #pragma unroll
            for (int t = 0; t < 4; t++) {
                int Ra = wm * 64 + t * 16 + lr;
                af[t]  = *reinterpret_cast<const bf16x8*>(Asm + Ra * 64 + ((ks * 4 + lg) ^ (Ra & 7)) * 8);
                int Rb = wn * 64 + t * 16 + lr;
                bfr[t] = *reinterpret_cast<const bf16x8*>(Bsm + Rb * 64 + ((ks * 4 + lg) ^ (Rb & 7)) * 8);
            }
            #pragma unroll
            for (int mt = 0; mt < 4; mt++) {
                #pragma unroll
                for (int nt = 0; nt < 4; nt++)
                    acc[mt][nt] = __builtin_amdgcn_mfma_f32_16x16x32_bf16(af[mt], bfr[nt], acc[mt][nt], 0, 0, 0);
            }
        }
    }
}

// ---------------- QKV projection: z=0 Q (scaled), z=1 K, z=2 V^T ----------------
__global__ __launch_bounds__(256) void gemm_qkv_kernel(
    const unsigned short* __restrict__ A, const unsigned short* __restrict__ WtBase,
    const float* __restrict__ bq, const float* __restrict__ bk, const float* __restrict__ bv,
    unsigned short* __restrict__ Qo, unsigned short* __restrict__ Ko, unsigned short* __restrict__ Vto)
{
    __shared__ unsigned short Asm[8192];
    __shared__ unsigned short Bsm[8192];
    const int z = blockIdx.z;
    const unsigned short* Wt = WtBase + (size_t)z * 1048576;
    const float* bias = (z == 0) ? bq : (z == 1) ? bk : bv;
    const int m0 = blockIdx.y * 128, n0 = blockIdx.x * 128;
    const int tid = threadIdx.x, lane = tid & 63, w = tid >> 6;
    const int wm = w >> 1, wn = w & 1, lr = lane & 15, lg = lane >> 4;
    f32x4 acc[4][4];
    f32x4 zero4 = {0.f, 0.f, 0.f, 0.f};
    #pragma unroll
    for (int i = 0; i < 4; i++)
        #pragma unroll
        for (int j = 0; j < 4; j++) acc[i][j] = zero4;
    gemm128_main(A, Wt, m0, n0, tid, Asm, Bsm, acc);

    const float qs = 0.125f * 1.44269504088896341f;  // 1/sqrt(64) * log2(e)
    #pragma unroll
    for (int mt = 0; mt < 4; mt++) {
        #pragma unroll
        for (int nt = 0; nt < 4; nt++) {
            int gn = n0 + wn * 64 + nt * 16 + lr;
            int h = gn >> 6, d = gn & 63;
            int rb = m0 + wm * 64 + mt * 16 + lg * 4;
            int b_ = rb >> 11, s = rb & 2047;
            float bv_ = bias[gn];
            if (z == 2) {
                u32x2 p;
                p.x = pack2bf(acc[mt][nt][0] + bv_, acc[mt][nt][1] + bv_);
                p.y = pack2bf(acc[mt][nt][2] + bv_, acc[mt][nt][3] + bv_);
                *reinterpret_cast<u32x2*>(Vto + ((size_t)(b_ * 16 + h) * 64 + d) * 2048 + s) = p;
            } else {
                unsigned short* dst = (z == 0) ? Qo : Ko;
                float sc_ = (z == 0) ? qs : 1.0f;
                #pragma unroll
                for (int r = 0; r < 4; r++)
                    dst[((size_t)(b_ * 16 + h) * 2048 + (s + r)) * 64 + d] = f2bf((acc[mt][nt][r] + bv_) * sc_);
            }
        }
    }
}

// ------- flash attention: swapped QK^T (32x32x16), in-register softmax -------
// (unchanged from round 3 — verified correct)
__global__ __launch_bounds__(256, 2) void attn_kernel(
    const unsigned short* __restrict__ Qg,
    const unsigned short* __restrict__ Kg,
    const unsigned short* __restrict__ Vtg,
    unsigned short* __restrict__ Og)
{
    __shared__ unsigned short Ksm[128][72];
    __shared__ unsigned short Vsm[64][136];

    const int tid = threadIdx.x, lane = tid & 63, w = tid >> 6;
    const int l31 = lane & 31, L = lane >> 5;
    const int bh = blockIdx.y, q0 = blockIdx.x * 128;
    const size_t kvbase = (size_t)bh * (2048 * 64);
    const size_t vtbase = (size_t)bh * (64 * 2048);

    {
        u32x4 qr[4];
        #pragma unroll
        for (int i = 0; i < 4; i++) {
            int ck = i * 256 + tid; int r = ck >> 3, c = (ck & 7) * 8;
            qr[i] = *reinterpret_cast<const u32x4*>(Qg + kvbase + (size_t)(q0 + r) * 64 + c);
        }
        #pragma unroll
        for (int i = 0; i < 4; i++) {
            int ck = i * 256 + tid; int r = ck >> 3, c = (ck & 7) * 8;
            *reinterpret_cast<u32x4*>(&Ksm[r][c]) = qr[i];
        }
    }
    __syncthreads();
    bf16x8 qf[4];
    #pragma unroll
    for (int ds = 0; ds < 4; ds++)
        qf[ds] = *reinterpret_cast<const bf16x8*>(&Ksm[w * 32 + l31][ds * 16 + L * 8]);
    __syncthreads();

    f32x16 oacc[2];
    #pragma unroll
    for (int dt = 0; dt < 2; dt++)
        #pragma unroll
        for (int j = 0; j < 16; j++) oacc[dt][j] = 0.f;
    float m_run = -3.0e38f, l_run = 0.f;

    u32x4 kreg[4], vreg[4];
#define LOAD_TILE(KV0)                                                                      \
    _Pragma("unroll")                                                                       \
    for (int i = 0; i < 4; i++) {                                                           \
        int ck = i * 256 + tid; int r = ck >> 3, c = (ck & 7) * 8;                          \
        kreg[i] = *reinterpret_cast<const u32x4*>(Kg + kvbase + (size_t)((KV0) + r) * 64 + c); \
        int dv = ck >> 4, cv = (ck & 15) * 8;                                               \
        vreg[i] = *reinterpret_cast<const u32x4*>(Vtg + vtbase + (size_t)dv * 2048 + (KV0) + cv); \
    }

    LOAD_TILE(0)
    for (int kt = 0; kt < 16; kt++) {
        #pragma unroll
        for (int i = 0; i < 4; i++) {
            int ck = i * 256 + tid; int r = ck >> 3, c = (ck & 7) * 8;
            *reinterpret_cast<u32x4*>(&Ksm[r][c]) = kreg[i];
            int dv = ck >> 4, cv = (ck & 15) * 8;
            *reinterpret_cast<u32x4*>(&Vsm[dv][cv]) = vreg[i];
        }
        __syncthreads();
        int kvn = (kt < 15) ? (kt + 1) * 128 : 0;
        LOAD_TILE(kvn)

        f32x16 sc[4];
        #pragma unroll
        for (int nt = 0; nt < 4; nt++) {
            #pragma unroll
            for (int j = 0; j < 16; j++) sc[nt][j] = 0.f;
            #pragma unroll
            for (int ds = 0; ds < 4; ds++) {
                bf16x8 kf = *reinterpret_cast<const bf16x8*>(&Ksm[nt * 32 + l31][ds * 16 + L * 8]);
                sc[nt] = __builtin_amdgcn_mfma_f32_32x32x16_bf16(kf, qf[ds], sc[nt], 0, 0, 0);
            }
        }

        float pmax = sc[0][0];
        #pragma unroll
        for (int nt = 0; nt < 4; nt++)
            #pragma unroll
            for (int j = 0; j < 16; j++) pmax = fmaxf(pmax, sc[nt][j]);
        pmax = fmaxf(pmax, __shfl_xor(pmax, 32));

        if (__any(pmax - m_run > 8.0f)) {
            float mnew = fmaxf(m_run, pmax);
            float f = __builtin_amdgcn_exp2f(m_run - mnew);
            l_run *= f;
            #pragma unroll
            for (int dt = 0; dt < 2; dt++)
                #pragma unroll
                for (int j = 0; j < 16; j++) oacc[dt][j] *= f;
            m_run = mnew;
        }

        float psum = 0.f;
        unsigned pdw[4][4][2];
        #pragma unroll
        for (int nt = 0; nt < 4; nt++) {
            float p[16];
            #pragma unroll
            for (int j = 0; j < 16; j++) {
                p[j] = __builtin_amdgcn_exp2f(sc[nt][j] - m_run);
                psum += p[j];
            }
            #pragma unroll
            for (int a = 0; a < 4; a++) {
                pdw[nt][a][0] = cvtpk(p[4 * a + 0], p[4 * a + 1]);
                pdw[nt][a][1] = cvtpk(p[4 * a + 2], p[4 * a + 3]);
            }
        }
        psum += __shfl_xor(psum, 32);
        l_run += psum;

        #pragma unroll
        for (int kt2 = 0; kt2 < 8; kt2++) {
            const int nt = kt2 >> 1, b2 = (kt2 & 1) * 2;
            unsigned own0  = L ? pdw[nt][b2 + 1][0] : pdw[nt][b2][0];
            unsigned own1  = L ? pdw[nt][b2 + 1][1] : pdw[nt][b2][1];
            unsigned send0 = L ? pdw[nt][b2][0]     : pdw[nt][b2 + 1][0];
            unsigned send1 = L ? pdw[nt][b2][1]     : pdw[nt][b2 + 1][1];
            unsigned recv0 = (unsigned)__shfl_xor((int)send0, 32);
            unsigned recv1 = (unsigned)__shfl_xor((int)send1, 32);
            u32x4 pf4;
            pf4.x = L ? recv0 : own0;
            pf4.y = L ? recv1 : own1;
            pf4.z = L ? own0  : recv0;
            pf4.w = L ? own1  : recv1;
            bf16x8 pfr = *reinterpret_cast<bf16x8*>(&pf4);
            #pragma unroll
            for (int dt = 0; dt < 2; dt++) {
                bf16x8 vf = *reinterpret_cast<const bf16x8*>(&Vsm[dt * 32 + l31][kt2 * 16 + L * 8]);
                oacc[dt] = __builtin_amdgcn_mfma_f32_32x32x16_bf16(vf, pfr, oacc[dt], 0, 0, 0);
            }
        }
        __syncthreads();
    }
#undef LOAD_TILE

    float inv = 1.0f / l_run;
    const int b_ = bh >> 4, h = bh & 15;
    const int s = q0 + w * 32 + l31;
    unsigned short* orow = Og + ((size_t)b_ * 2048 + s) * 1024 + h * 64;
    #pragma unroll
    for (int dt = 0; dt < 2; dt++) {
        #pragma unroll
        for (int g = 0; g < 4; g++) {
            u32x2 pp;
            pp.x = cvtpk(oacc[dt][4 * g + 0] * inv, oacc[dt][4 * g + 1] * inv);
            pp.y = cvtpk(oacc[dt][4 * g + 2] * inv, oacc[dt][4 * g + 3] * inv);
            *reinterpret_cast<u32x2*>(orow + dt * 32 + g * 8 + 4 * L) = pp;
        }
    }
}

// ---------------- output projection: Obuf @ Wo^T + bo -> fp32 out ----------------
__global__ __launch_bounds__(256) void gemm_out_kernel(
    const unsigned short* __restrict__ A, const unsigned short* __restrict__ Wt,
    const float* __restrict__ bias, float* __restrict__ out)
{
    __shared__ unsigned short Asm[8192];
    __shared__ unsigned short Bsm[8192];
    const int m0 = blockIdx.y * 128, n0 = blockIdx.x * 128;
    const int tid = threadIdx.x, lane = tid & 63, w = tid >> 6;
    const int wm = w >> 1, wn = w & 1, lr = lane & 15, lg = lane >> 4;
    f32x4 acc[4][4];
    f32x4 zero4 = {0.f, 0.f, 0.f, 0.f};
    #pragma unroll
    for (int i = 0; i < 4; i++)
        #pragma unroll
        for (int j = 0; j < 4; j++) acc[i][j] = zero4;
    gemm128_main(A, Wt, m0, n0, tid, Asm, Bsm, acc);
    #pragma unroll
    for (int mt = 0; mt < 4; mt++) {
        #pragma unroll
        for (int nt = 0; nt < 4; nt++) {
            int gn = n0 + wn * 64 + nt * 16 + lr;
            float bv_ = bias[gn];
            int rb = m0 + wm * 64 + mt * 16 + lg * 4;
            #pragma unroll
            for (int r = 0; r < 4; r++)
                out[(size_t)(rb + r) * 1024 + gn] = acc[mt][nt][r] + bv_;
        }
    }
}

extern "C" void kernel_launch(void* const* d_in, const int* in_sizes, int n_in,
                              void* d_out, int out_size, void* d_ws, size_t ws_size,
                              hipStream_t stream) {
    const float* x  = (const float*)d_in[0];
    const float* Wq = (const float*)d_in[1];
    const float* bq = (const float*)d_in[2];
    const float* Wk = (const float*)d_in[3];
    const float* bk = (const float*)d_in[4];
    const float* Wv = (const float*)d_in[5];
    const float* bv = (const float*)d_in[6];
    const float* Wo = (const float*)d_in[7];
    const float* bo = (const float*)d_in[8];
    float* out = (float*)d_out;

    if (ws_size < (size_t)25165824 * 2) return;  // need 48 MB
    unsigned short* ws  = (unsigned short*)d_ws;
    unsigned short* xbf = ws;                    // [4096][1024]
    unsigned short* wt  = ws + 4194304;          // 4x [1024][1024] transposed
    unsigned short* Qb  = ws + 8388608;          // [B,H,S,D] (pre-scaled)
    unsigned short* Kb  = ws + 12582912;         // [B,H,S,D]
    unsigned short* Vtb = ws + 16777216;         // [B,H,D,S]
    unsigned short* Ob  = ws + 20971520;         // [B,S,E]

    cvt_x_kernel<<<2048, 256, 0, stream>>>(x, xbf);
    cvt_w_kernel<<<dim3(256, 4), 256, 0, stream>>>(Wq, Wk, Wv, Wo, wt);
    gemm_qkv_kernel<<<dim3(8, 32, 3), 256, 0, stream>>>(xbf, wt, bq, bk, bv, Qb, Kb, Vtb);
    attn_kernel<<<dim3(16, 32), 256, 0, stream>>>(Qb, Kb, Vtb, Ob);
    gemm_out_kernel<<<dim3(8, 32), 256, 0, stream>>>(Ob, wt + 3 * 1048576, bo, out);
}